// Round 12
// baseline (133.002 us; speedup 1.0000x reference)
//
#include <hip/hip_runtime.h>
#include <hip/hip_bf16.h>

typedef _Float16 f16x8 __attribute__((ext_vector_type(8)));
typedef _Float16 f16x4 __attribute__((ext_vector_type(4)));
typedef float f32x4 __attribute__((ext_vector_type(4)));
typedef unsigned short u16x8 __attribute__((ext_vector_type(8)));
typedef unsigned short u16x4 __attribute__((ext_vector_type(4)));

constexpr int B_ = 2, M_ = 5, C_ = 64, H_ = 128, W_ = 256;
constexpr int HW_ = H_ * W_;               // 32768
constexpr int PLANE_ = C_ * HW_;           // 2097152
constexpr int NIMG_ = B_ * M_;             // 10

// workspace layout (bytes) — xin eliminated
constexpr size_t OFF_WL1 = 256;
constexpr size_t SZ_WL   = (size_t)9 * 64 * 64 * 2;             // 73,728
constexpr size_t OFF_WL2 = OFF_WL1 + SZ_WL;
constexpr size_t OFF_N1  = OFF_WL2 + SZ_WL;
constexpr size_t SZ_N    = (size_t)NIMG_ * HW_ * 64 * 2;        // 41,943,040
constexpr size_t OFF_N2  = OFF_N1 + SZ_N;

// ---------------- in-kernel dtype sniff (every wave, ~20 cyc) -----------------
__device__ inline bool sniff(const void* pts) {
  int lane = threadIdx.x & 63;
  unsigned short v = ((const unsigned short*)pts)[2 * lane];
  int e = (v >> 7) & 0xFF;
  unsigned long long mask = __ballot(e >= 100 && e <= 140);
  return __popcll(mask) >= 48;
}

// ---------- W [oc][ic][3][3] -> swizzled fp16 [tap][oc][ic] -------------------
__global__ void wprep_kernel(const void* __restrict__ W1, const void* __restrict__ W2,
                             _Float16* __restrict__ wl1, _Float16* __restrict__ wl2,
                             const void* __restrict__ pts) {
  const bool isb = sniff(pts);
  int idx = blockIdx.x * 256 + threadIdx.x;  // 0..36863, grid.y selects matrix
  const void* Wsrc = blockIdx.y ? W2 : W1;
  _Float16* dst = blockIdx.y ? wl2 : wl1;
  int tap = idx >> 12;
  int oc = (idx >> 6) & 63;
  int ic = idx & 63;
  size_t s = (size_t)(oc * 64 + ic) * 9 + tap;
  float v = isb ? __bfloat162float(((const __hip_bfloat16*)Wsrc)[s])
                : ((const float*)Wsrc)[s];
  dst[(tap * 4096 + oc * 64 + ic) ^ ((oc & 7) << 3)] = (_Float16)v;
}

// ---------------- persistent fused conv: both convs, oc-half per block --------
// grid = 256 blocks x 512 threads (8 waves; 1 block/CU; reg cap 256).
// Stages DIRECTLY from NCHW pts (fp32|bf16): per staging unit (c8,r,p) the
// thread gathers 8 channel-strided scalars (wave-coalesced across p), converts
// to f16, and ds_writes the same swizzled sIn layout prep used to produce.
// Bounds-check replaces the border-zero pass. Read side / MFMA / epilogue
// identical to the verified round-10/11 kernel.
__global__ __launch_bounds__(512, 2)
void conv_fused(const void* __restrict__ pts,
                const _Float16* __restrict__ wl1, const _Float16* __restrict__ wl2,
                const void* __restrict__ bias1, const void* __restrict__ bias2,
                _Float16* __restrict__ n1, _Float16* __restrict__ n2) {
  __shared__ _Float16 sIn[10 * 66 * 64];    // 84,480 B, swizzled rows of 66 px
  __shared__ _Float16 sW[2 * 9 * 32 * 64];  // 73,728 B: [conv][tap][oc32][ic64]

  const int t = threadIdx.x;
  const int och = blockIdx.x & 1;
  const int pid = blockIdx.x >> 1;          // 0..127

  const int l = t & 63, wv = t >> 6;        // wv 0..7 = row
  const int lr = l & 15, hi = l >> 4;
  const bool isb = sniff(pts);

  // --- stage weights once (linear copy preserves pre-applied swizzle) ---
#pragma unroll
  for (int c = 0; c < 2; ++c) {
    const f16x8* src = (const f16x8*)((const char*)(c ? wl2 : wl1) + och * 4096);
    f16x8* dst = (f16x8*)sW + c * 2304;
    for (int i = t; i < 2304; i += 512) {
      int tap = i >> 8, e = i & 255;
      dst[i] = src[tap * 512 + e];
    }
  }

  // bias vectors: lane owns oc quad och*32 + ob*16 + hi*4 .. +3
  f32x4 bv1[2], bv2[2];
#pragma unroll
  for (int ob = 0; ob < 2; ++ob) {
    int oc0 = och * 32 + ob * 16 + hi * 4;
    if (isb) {
      u16x4 q1 = *(const u16x4*)((const unsigned short*)bias1 + oc0);
      u16x4 q2 = *(const u16x4*)((const unsigned short*)bias2 + oc0);
#pragma unroll
      for (int r = 0; r < 4; ++r) {
        bv1[ob][r] = __uint_as_float(((unsigned)q1[r]) << 16);
        bv2[ob][r] = __uint_as_float(((unsigned)q2[r]) << 16);
      }
    } else {
      bv1[ob] = *(const f32x4*)((const float*)bias1 + oc0);
      bv2[ob] = *(const f32x4*)((const float*)bias2 + oc0);
    }
  }

  // swizzled channel-offset terms (read side, unchanged)
  int c2a[3][2], c2b[2];
#pragma unroll
  for (int dx = 0; dx < 3; ++dx) {
    int key = (((l & 7) + dx) & 7) << 4;
#pragma unroll
    for (int kw = 0; kw < 2; ++kw) c2a[dx][kw] = (hi * 16 + kw * 64) ^ key;
  }
#pragma unroll
  for (int kw = 0; kw < 2; ++kw) c2b[kw] = (hi * 16 + kw * 64) ^ ((l & 7) << 4);

  // --- staging geometry (constant across tiles): unit i = c8*660 + r*66 + p ---
  // r in [0,10) input rows (h = hy*8-1+r), p in [0,66) px (w = wx*64-1+p),
  // c8 = channel octet. lds byte = r*8448 + p*128 + (c8*16 ^ ((p&7)<<4)) —
  // identical to what prep_kernel + linear copy produced.
  int rr[11], ppu[11], lof[11], gof[11];
#pragma unroll
  for (int u = 0; u < 11; ++u) {
    int i = u * 512 + t;
    if (i >= 5280) i = 5279;  // dummy for unused slots (guarded below)
    int c8 = i / 660, rem = i - c8 * 660;
    int r = rem / 66, p = rem - r * 66;
    rr[u] = r;
    ppu[u] = p;
    lof[u] = r * 8448 + p * 128 + ((c8 * 16) ^ ((p & 7) << 4));
    gof[u] = c8 * 8 * HW_ + r * W_ + p;
  }

  f16x8 rg[11];
  auto issue = [&](int tt) {
    int img = tt >> 6, hy = (tt >> 2) & 15, wx = tt & 3;
    int h0 = hy * 8 - 1, p0 = wx * 64 - 1;
    int tbase = img * PLANE_ + h0 * W_ + p0;
#pragma unroll
    for (int u = 0; u < 11; ++u) {
      if (u == 10 && (5120 + t) >= 5280) continue;
      int hin = h0 + rr[u];
      int pin = p0 + ppu[u];
      bool ok = ((unsigned)hin < (unsigned)H_) && ((unsigned)pin < (unsigned)W_);
      int g = tbase + gof[u];
      f16x8 v = {};
      if (ok) {
        if (isb) {
          const unsigned short* sp = (const unsigned short*)pts + g;
#pragma unroll
          for (int jj = 0; jj < 8; ++jj)
            v[jj] = (_Float16)__uint_as_float(((unsigned)sp[(size_t)jj * HW_]) << 16);
        } else {
          const float* sp = (const float*)pts + g;
#pragma unroll
          for (int jj = 0; jj < 8; ++jj)
            v[jj] = (_Float16)sp[(size_t)jj * HW_];
        }
      }
      rg[u] = v;
    }
  };

  issue(pid);  // tile for j=0

  const char* sInB = (const char*)sIn;
  const char* sWB = (const char*)sW;

  __syncthreads();  // weights staged before first compute

#pragma unroll 1
  for (int j = 0; j < 5; ++j) {
    const int tt = pid + 128 * j;

    // ds_write staged tile (swizzled positions)
#pragma unroll
    for (int u = 0; u < 11; ++u) {
      if (u == 10 && (5120 + t) >= 5280) continue;
      *(f16x8*)((char*)sIn + lof[u]) = rg[u];
    }
    // ready-barrier: only LDS writes must be visible; vmcnt stays in flight
    asm volatile("s_waitcnt lgkmcnt(0)" ::: "memory");
    __builtin_amdgcn_s_barrier();

    if (j < 4) issue(pid + 128 * (j + 1));  // T14: next tile in flight

    f32x4 acc1[4][2], acc2[4][2];
#pragma unroll
    for (int pa = 0; pa < 4; ++pa)
#pragma unroll
      for (int ob = 0; ob < 2; ++ob) {
        acc1[pa][ob] = bv1[ob];
        acc2[pa][ob] = bv2[ob];
      }

    __builtin_amdgcn_s_setprio(1);
#pragma unroll
    for (int ky = 0; ky < 3; ++ky) {
#pragma unroll
      for (int kx = 0; kx < 3; ++kx) {
        const int tap = ky * 3 + kx;
#pragma unroll
        for (int kw = 0; kw < 2; ++kw) {
          f16x8 a[4], b1a, b1b, b2a, b2b;
#pragma unroll
          for (int pa = 0; pa < 4; ++pa)
            a[pa] = *(const f16x8*)(sInB + ((wv + ky) * 8448 + (pa * 16 + lr + kx) * 128 + c2a[kx][kw]));
          b1a = *(const f16x8*)(sWB + tap * 4096 + lr * 128 + c2b[kw]);
          b1b = *(const f16x8*)(sWB + tap * 4096 + (16 + lr) * 128 + c2b[kw]);
          b2a = *(const f16x8*)(sWB + 36864 + tap * 4096 + lr * 128 + c2b[kw]);
          b2b = *(const f16x8*)(sWB + 36864 + tap * 4096 + (16 + lr) * 128 + c2b[kw]);
          // SWAPPED operands: D[oc][px]
#pragma unroll
          for (int pa = 0; pa < 4; ++pa) {
            acc1[pa][0] = __builtin_amdgcn_mfma_f32_16x16x32_f16(b1a, a[pa], acc1[pa][0], 0, 0, 0);
            acc1[pa][1] = __builtin_amdgcn_mfma_f32_16x16x32_f16(b1b, a[pa], acc1[pa][1], 0, 0, 0);
            acc2[pa][0] = __builtin_amdgcn_mfma_f32_16x16x32_f16(b2a, a[pa], acc2[pa][0], 0, 0, 0);
            acc2[pa][1] = __builtin_amdgcn_mfma_f32_16x16x32_f16(b2b, a[pa], acc2[pa][1], 0, 0, 0);
          }
        }
      }
    }
    __builtin_amdgcn_s_setprio(0);

    // release-barrier: ds_reads retired via MFMA data deps
    __builtin_amdgcn_s_barrier();

    // epilogue after the barrier (overlaps next iteration's ds_write).
    // lane holds: px = pa*16 + lr, oc quad = och*32 + ob*16 + hi*4 + r.
    // tanh(3x) = 1 - 2*rcp(1+exp2(8.656*u)); packed 4xf16 = one 8-B store.
    {
      int img = tt >> 6, hy = (tt >> 2) & 15, wx = tt & 3;
      size_t pxbase = ((size_t)(img * H_ + hy * 8 + wv) * W_ + wx * 64 + lr) * 64
                      + och * 32 + hi * 4;
#pragma unroll
      for (int pa = 0; pa < 4; ++pa)
#pragma unroll
        for (int ob = 0; ob < 2; ++ob) {
          size_t o = pxbase + (size_t)pa * (16 * 64) + ob * 16;
          f16x4 p1, p2;
#pragma unroll
          for (int r = 0; r < 4; ++r) {
            float e1 = __builtin_exp2f(acc1[pa][ob][r] * 8.656170245f);
            p1[r] = (_Float16)fmaf(-2.f, __builtin_amdgcn_rcpf(1.f + e1), 1.f);
            float e2 = __builtin_exp2f(acc2[pa][ob][r] * 8.656170245f);
            p2[r] = (_Float16)fmaf(-2.f, __builtin_amdgcn_rcpf(1.f + e2), 1.f);
          }
          *(f16x4*)(n1 + o) = p1;
          *(f16x4*)(n2 + o) = p2;
        }
    }
  }
}

// ---------------- gram + antisym + sigmoid + eye + row-normalize --------------
// 8 lanes cooperate per pixel: lane octet j owns channels 8j..8j+7.
__global__ __launch_bounds__(256)
void pairwise_kernel(const _Float16* __restrict__ n1, const _Float16* __restrict__ n2,
                     void* __restrict__ out, const void* __restrict__ pts) {
  const bool isb = sniff(pts);
  int tid = blockIdx.x * 256 + threadIdx.x;
  int gp = tid >> 3;               // pixel id 0 .. B*HW-1
  int j = tid & 7;                 // channel octet
  int b = gp >> 15, px = gp & (HW_ - 1);
  const _Float16* p1 = n1 + ((size_t)(b * M_) * HW_ + px) * 64 + j * 8;
  const _Float16* p2 = n2 + ((size_t)(b * M_) * HW_ + px) * 64 + j * 8;

  f16x8 A[M_], Bv[M_];
#pragma unroll
  for (int m = 0; m < M_; ++m) {
    A[m]  = *(const f16x8*)(p1 + (size_t)m * PLANE_);
    Bv[m] = *(const f16x8*)(p2 + (size_t)m * PLANE_);
  }

  float s[M_][M_];
#pragma unroll
  for (int m = 0; m < M_; ++m)
#pragma unroll
    for (int n = 0; n < M_; ++n) s[m][n] = 0.f;

#pragma unroll
  for (int jj = 0; jj < 8; ++jj)
#pragma unroll
    for (int m = 0; m < M_; ++m)
#pragma unroll
      for (int n = 0; n < M_; ++n)
        s[m][n] += (float)A[m][jj] * (float)Bv[n][jj];

#pragma unroll
  for (int m = 0; m < M_; ++m)
#pragma unroll
    for (int n = 0; n < M_; ++n) {
      s[m][n] += __shfl_xor(s[m][n], 1);
      s[m][n] += __shfl_xor(s[m][n], 2);
      s[m][n] += __shfl_xor(s[m][n], 4);
    }

  float adj[M_][M_], rs[M_];
#pragma unroll
  for (int m = 0; m < M_; ++m) {
    float r = 0.f;
#pragma unroll
    for (int n = 0; n < M_; ++n) {
      float a = s[m][n] - s[n][m];
      float e = __builtin_exp2f(a * -4.328085123f);  // exp(-3a)
      float v = __builtin_amdgcn_rcpf(1.f + e);
      if (m == n) v += 1.f;
      adj[m][n] = v;
      r += v;
    }
    rs[m] = r;
  }

  for (int k = j; k < 25; k += 8) {
    int m = k / 5, n = k - m * 5;
    float v = adj[m][n] * __builtin_amdgcn_rcpf(rs[m]);
    size_t o = ((size_t)((b * M_ + m) * M_ + n)) * HW_ + px;
    if (isb) ((__hip_bfloat16*)out)[o] = __float2bfloat16(v);
    else     ((float*)out)[o] = v;
  }
}

// ---------------- launch ----------------
extern "C" void kernel_launch(void* const* d_in, const int* in_sizes, int n_in,
                              void* d_out, int out_size, void* d_ws, size_t ws_size,
                              hipStream_t stream) {
  const void* pts = d_in[0];
  const void* W1  = d_in[1];
  const void* b1  = d_in[2];
  const void* W2  = d_in[3];
  const void* b2  = d_in[4];

  char* ws = (char*)d_ws;
  _Float16* wl1 = (_Float16*)(ws + OFF_WL1);
  _Float16* wl2 = (_Float16*)(ws + OFF_WL2);
  _Float16* n1  = (_Float16*)(ws + OFF_N1);
  _Float16* n2  = (_Float16*)(ws + OFF_N2);

  wprep_kernel<<<dim3(144, 2), dim3(256), 0, stream>>>(W1, W2, wl1, wl2, pts);
  conv_fused<<<dim3(256), dim3(512), 0, stream>>>(pts, wl1, wl2, b1, b2, n1, n2);
  pairwise_kernel<<<dim3(B_ * HW_ * 8 / 256), dim3(256), 0, stream>>>(n1, n2, d_out, pts);
}

// Round 13
// 111.649 us; speedup vs baseline: 1.1912x; 1.1912x over previous
//
#include <hip/hip_runtime.h>
#include <hip/hip_bf16.h>

typedef _Float16 f16x8 __attribute__((ext_vector_type(8)));
typedef _Float16 f16x4 __attribute__((ext_vector_type(4)));
typedef float f32x4 __attribute__((ext_vector_type(4)));
typedef unsigned short u16x8 __attribute__((ext_vector_type(8)));
typedef unsigned short u16x4 __attribute__((ext_vector_type(4)));

constexpr int B_ = 2, M_ = 5, C_ = 64, H_ = 128, W_ = 256;
constexpr int HW_ = H_ * W_;               // 32768
constexpr int PLANE_ = C_ * HW_;           // 2097152
constexpr int NIMG_ = B_ * M_;             // 10
constexpr int PH_ = H_ + 2, PW_ = W_ + 2;  // 130, 258

// workspace layout (bytes)
constexpr size_t OFF_XIN = 256;
constexpr size_t SZ_XIN  = (size_t)NIMG_ * PH_ * PW_ * 64 * 2;  // 42,931,200
constexpr size_t OFF_WL1 = OFF_XIN + SZ_XIN;
constexpr size_t SZ_WL   = (size_t)9 * 64 * 64 * 2;             // 73,728
constexpr size_t OFF_WL2 = OFF_WL1 + SZ_WL;
constexpr size_t OFF_N1  = OFF_WL2 + SZ_WL;
constexpr size_t SZ_N    = (size_t)NIMG_ * HW_ * 64 * 2;        // 41,943,040
constexpr size_t OFF_N2  = OFF_N1 + SZ_N;

// ---------------- in-kernel dtype sniff (every wave, ~20 cyc) -----------------
// pts ~ N(0,1). bf16: every u16 has exponent ~[117,129]. fp32: even u16s are
// low mantissa halves (uniform bits) -> exponent field rarely in range.
__device__ inline bool sniff(const void* pts) {
  int lane = threadIdx.x & 63;
  unsigned short v = ((const unsigned short*)pts)[2 * lane];
  int e = (v >> 7) & 0xFF;
  unsigned long long mask = __ballot(e >= 100 && e <= 140);
  return __popcll(mask) >= 48;
}

// -------- NCHW (fp32|bf16) -> padded swizzled NHWC fp16; z==10: weights+border
__global__ __launch_bounds__(256) void prep_kernel(const void* __restrict__ in,
                                                   _Float16* __restrict__ xin,
                                                   const void* __restrict__ W1,
                                                   const void* __restrict__ W2,
                                                   _Float16* __restrict__ wl1,
                                                   _Float16* __restrict__ wl2) {
  __shared__ float sT[64 * 72];
  const int t = threadIdx.x;
  const bool isb = sniff(in);

  if (blockIdx.z == 10) {
    int s = blockIdx.y * 4 + blockIdx.x;   // 0..511
    if (s < 288) {
      // weight transform: W [oc][ic][3][3] -> swizzled fp16 [tap][oc][ic]
      int which = s / 144, blk = s - which * 144;
      int idx = blk * 256 + t;
      const void* Wsrc = which ? W2 : W1;
      _Float16* dst = which ? wl2 : wl1;
      int tap = idx >> 12;
      int oc = (idx >> 6) & 63;
      int ic = idx & 63;
      size_t so = (size_t)(oc * 64 + ic) * 9 + tap;
      float v = isb ? __bfloat162float(((const __hip_bfloat16*)Wsrc)[so])
                    : ((const float*)Wsrc)[so];
      dst[(tap * 4096 + oc * 64 + ic) ^ ((oc & 7) << 3)] = (_Float16)v;
    } else if (s < 320) {
      // border zeroing of the padded NHWC buffer (7720 border pixels)
      int idx = (s - 288) * 256 + t;
      if (idx >= NIMG_ * 772) return;
      int img = idx / 772, r = idx - img * 772;
      int ph, pw;
      if (r < 258)      { ph = 0;            pw = r; }
      else if (r < 516) { ph = PH_ - 1;      pw = r - 258; }
      else if (r < 644) { ph = r - 516 + 1;  pw = 0; }
      else              { ph = r - 644 + 1;  pw = PW_ - 1; }
      f16x8 z = {};
      _Float16* p = xin + ((size_t)(img * PH_ + ph) * PW_ + pw) * 64;
#pragma unroll
      for (int c8 = 0; c8 < 8; ++c8) *(f16x8*)(p + c8 * 8) = z;
    }
    return;
  }

  const int wt = blockIdx.x, h = blockIdx.y, img = blockIdx.z;
  const size_t ibase = (size_t)img * PLANE_ + (size_t)h * W_ + wt * 64;
  if (isb) {
#pragma unroll
    for (int k = 0; k < 2; ++k) {          // 512 units of 8 bf16
      int u = k * 256 + t;
      int ic = u >> 3, wo = u & 7;
      const unsigned short* p = (const unsigned short*)in + ibase + (size_t)ic * HW_ + wo * 8;
      u16x8 v = *(const u16x8*)p;
#pragma unroll
      for (int j = 0; j < 8; ++j)
        sT[ic * 72 + wo * 8 + j] = __uint_as_float(((unsigned)v[j]) << 16);
    }
  } else {
#pragma unroll
    for (int k = 0; k < 4; ++k) {          // 1024 units of 4 fp32
      int u = k * 256 + t;
      int ic = u >> 4, wq = u & 15;
      const float* p = (const float*)in + ibase + (size_t)ic * HW_ + wq * 4;
      f32x4 v = *(const f32x4*)p;
      *(f32x4*)&sT[ic * 72 + wq * 4] = v;
    }
  }
  __syncthreads();
#pragma unroll
  for (int k = 0; k < 2; ++k) {
    int idx = k * 256 + t;
    int w = idx >> 3, c8 = idx & 7;
    f16x8 vv;
#pragma unroll
    for (int j = 0; j < 8; ++j) vv[j] = (_Float16)sT[(c8 * 8 + j) * 72 + w];
    int pw = wt * 64 + w + 1;
    size_t rowbase = ((size_t)(img * PH_ + (h + 1)) * PW_ + pw) * 128;  // bytes
    int off = (c8 * 16) ^ ((pw & 7) << 4);
    *(f16x8*)((char*)xin + rowbase + off) = vv;
  }
}

// ---------------- persistent fused conv: both convs, oc-half per block --------
// grid = 256 blocks x 512 threads (8 waves; 1 block/CU; reg cap 256).
// 2 barriers/tile, swapped MFMA operands -> D[oc][px], packed f16x4 epilogue
// stores, T14 register prefetch, T5 setprio.
__global__ __launch_bounds__(512, 2)
void conv_fused(const _Float16* __restrict__ xin,
                const _Float16* __restrict__ wl1, const _Float16* __restrict__ wl2,
                const void* __restrict__ bias1, const void* __restrict__ bias2,
                const void* __restrict__ pts,
                _Float16* __restrict__ n1, _Float16* __restrict__ n2) {
  __shared__ _Float16 sIn[10 * 66 * 64];    // 84,480 B, swizzled rows of 66 px
  __shared__ _Float16 sW[2 * 9 * 32 * 64];  // 73,728 B: [conv][tap][oc32][ic64]

  const int t = threadIdx.x;
  const int och = blockIdx.x & 1;
  const int pid = blockIdx.x >> 1;          // 0..127

  const int l = t & 63, wv = t >> 6;        // wv 0..7 = row
  const int lr = l & 15, hi = l >> 4;
  const bool isb = sniff(pts);

  // --- stage weights once (linear copy preserves pre-applied swizzle) ---
#pragma unroll
  for (int c = 0; c < 2; ++c) {
    const f16x8* src = (const f16x8*)((const char*)(c ? wl2 : wl1) + och * 4096);
    f16x8* dst = (f16x8*)sW + c * 2304;
    for (int i = t; i < 2304; i += 512) {
      int tap = i >> 8, e = i & 255;
      dst[i] = src[tap * 512 + e];
    }
  }

  // bias vectors: lane owns oc quad och*32 + ob*16 + hi*4 .. +3
  f32x4 bv1[2], bv2[2];
#pragma unroll
  for (int ob = 0; ob < 2; ++ob) {
    int oc0 = och * 32 + ob * 16 + hi * 4;
    if (isb) {
      u16x4 q1 = *(const u16x4*)((const unsigned short*)bias1 + oc0);
      u16x4 q2 = *(const u16x4*)((const unsigned short*)bias2 + oc0);
#pragma unroll
      for (int r = 0; r < 4; ++r) {
        bv1[ob][r] = __uint_as_float(((unsigned)q1[r]) << 16);
        bv2[ob][r] = __uint_as_float(((unsigned)q2[r]) << 16);
      }
    } else {
      bv1[ob] = *(const f32x4*)((const float*)bias1 + oc0);
      bv2[ob] = *(const f32x4*)((const float*)bias2 + oc0);
    }
  }

  // swizzled channel-offset terms
  int c2a[3][2], c2b[2];
#pragma unroll
  for (int dx = 0; dx < 3; ++dx) {
    int key = (((l & 7) + dx) & 7) << 4;
#pragma unroll
    for (int kw = 0; kw < 2; ++kw) c2a[dx][kw] = (hi * 16 + kw * 64) ^ key;
  }
#pragma unroll
  for (int kw = 0; kw < 2; ++kw) c2b[kw] = (hi * 16 + kw * 64) ^ ((l & 7) << 4);

  // --- register staging: tile = 5280 f16x8; 11 regs/thread (512 thr) ---
  f16x8 rg[11];
  auto issue = [&](int tt) {
    int img = tt >> 6, hy = (tt >> 2) & 15, wx = tt & 3;
    const f16x8* base = (const f16x8*)(xin + ((size_t)(img * PH_ + hy * 8) * PW_ + wx * 64) * 64);
#pragma unroll
    for (int u = 0; u < 11; ++u) {
      int i = u * 512 + t;
      if (u < 10 || i < 5280) {
        int r = i / 528, cc = i - r * 528;
        rg[u] = base[(size_t)r * (PW_ * 8) + cc];
      }
    }
  };

  issue(pid);  // tile for j=0

  const char* sInB = (const char*)sIn;
  const char* sWB = (const char*)sW;

  __syncthreads();  // weights staged before first compute

#pragma unroll 1
  for (int j = 0; j < 5; ++j) {
    const int tt = pid + 128 * j;

    // ds_write staged tile
#pragma unroll
    for (int u = 0; u < 11; ++u) {
      int i = u * 512 + t;
      if (u < 10 || i < 5280) ((f16x8*)sIn)[i] = rg[u];
    }
    // ready-barrier: only LDS writes must be visible; vmcnt stays in flight
    asm volatile("s_waitcnt lgkmcnt(0)" ::: "memory");
    __builtin_amdgcn_s_barrier();

    if (j < 4) issue(pid + 128 * (j + 1));  // T14: next tile in flight

    f32x4 acc1[4][2], acc2[4][2];
#pragma unroll
    for (int pa = 0; pa < 4; ++pa)
#pragma unroll
      for (int ob = 0; ob < 2; ++ob) {
        acc1[pa][ob] = bv1[ob];
        acc2[pa][ob] = bv2[ob];
      }

    __builtin_amdgcn_s_setprio(1);
#pragma unroll
    for (int ky = 0; ky < 3; ++ky) {
#pragma unroll
      for (int kx = 0; kx < 3; ++kx) {
        const int tap = ky * 3 + kx;
#pragma unroll
        for (int kw = 0; kw < 2; ++kw) {
          f16x8 a[4], b1a, b1b, b2a, b2b;
#pragma unroll
          for (int pa = 0; pa < 4; ++pa)
            a[pa] = *(const f16x8*)(sInB + ((wv + ky) * 8448 + (pa * 16 + lr + kx) * 128 + c2a[kx][kw]));
          b1a = *(const f16x8*)(sWB + tap * 4096 + lr * 128 + c2b[kw]);
          b1b = *(const f16x8*)(sWB + tap * 4096 + (16 + lr) * 128 + c2b[kw]);
          b2a = *(const f16x8*)(sWB + 36864 + tap * 4096 + lr * 128 + c2b[kw]);
          b2b = *(const f16x8*)(sWB + 36864 + tap * 4096 + (16 + lr) * 128 + c2b[kw]);
          // SWAPPED operands: D[oc][px]
#pragma unroll
          for (int pa = 0; pa < 4; ++pa) {
            acc1[pa][0] = __builtin_amdgcn_mfma_f32_16x16x32_f16(b1a, a[pa], acc1[pa][0], 0, 0, 0);
            acc1[pa][1] = __builtin_amdgcn_mfma_f32_16x16x32_f16(b1b, a[pa], acc1[pa][1], 0, 0, 0);
            acc2[pa][0] = __builtin_amdgcn_mfma_f32_16x16x32_f16(b2a, a[pa], acc2[pa][0], 0, 0, 0);
            acc2[pa][1] = __builtin_amdgcn_mfma_f32_16x16x32_f16(b2b, a[pa], acc2[pa][1], 0, 0, 0);
          }
        }
      }
    }
    __builtin_amdgcn_s_setprio(0);

    // release-barrier: ds_reads retired via MFMA data deps
    __builtin_amdgcn_s_barrier();

    // epilogue after the barrier (overlaps next iteration's ds_write).
    // lane holds: px = pa*16 + lr, oc quad = och*32 + ob*16 + hi*4 + r.
    // tanh(3x) = 1 - 2*rcp(1+exp2(8.656*u)); packed 4xf16 = one 8-B store.
    {
      int img = tt >> 6, hy = (tt >> 2) & 15, wx = tt & 3;
      size_t pxbase = ((size_t)(img * H_ + hy * 8 + wv) * W_ + wx * 64 + lr) * 64
                      + och * 32 + hi * 4;
#pragma unroll
      for (int pa = 0; pa < 4; ++pa)
#pragma unroll
        for (int ob = 0; ob < 2; ++ob) {
          size_t o = pxbase + (size_t)pa * (16 * 64) + ob * 16;
          f16x4 p1, p2;
#pragma unroll
          for (int r = 0; r < 4; ++r) {
            float e1 = __builtin_exp2f(acc1[pa][ob][r] * 8.656170245f);
            p1[r] = (_Float16)fmaf(-2.f, __builtin_amdgcn_rcpf(1.f + e1), 1.f);
            float e2 = __builtin_exp2f(acc2[pa][ob][r] * 8.656170245f);
            p2[r] = (_Float16)fmaf(-2.f, __builtin_amdgcn_rcpf(1.f + e2), 1.f);
          }
          *(f16x4*)(n1 + o) = p1;
          *(f16x4*)(n2 + o) = p2;
        }
    }
  }
}

// ---------------- gram + antisym + sigmoid + eye + row-normalize --------------
// 8 lanes cooperate per pixel: lane octet j owns channels 8j..8j+7.
__global__ __launch_bounds__(256)
void pairwise_kernel(const _Float16* __restrict__ n1, const _Float16* __restrict__ n2,
                     void* __restrict__ out, const void* __restrict__ pts) {
  const bool isb = sniff(pts);
  int tid = blockIdx.x * 256 + threadIdx.x;
  int gp = tid >> 3;               // pixel id 0 .. B*HW-1
  int j = tid & 7;                 // channel octet
  int b = gp >> 15, px = gp & (HW_ - 1);
  const _Float16* p1 = n1 + ((size_t)(b * M_) * HW_ + px) * 64 + j * 8;
  const _Float16* p2 = n2 + ((size_t)(b * M_) * HW_ + px) * 64 + j * 8;

  f16x8 A[M_], Bv[M_];
#pragma unroll
  for (int m = 0; m < M_; ++m) {
    A[m]  = *(const f16x8*)(p1 + (size_t)m * PLANE_);
    Bv[m] = *(const f16x8*)(p2 + (size_t)m * PLANE_);
  }

  float s[M_][M_];
#pragma unroll
  for (int m = 0; m < M_; ++m)
#pragma unroll
    for (int n = 0; n < M_; ++n) s[m][n] = 0.f;

#pragma unroll
  for (int jj = 0; jj < 8; ++jj)
#pragma unroll
    for (int m = 0; m < M_; ++m)
#pragma unroll
      for (int n = 0; n < M_; ++n)
        s[m][n] += (float)A[m][jj] * (float)Bv[n][jj];

#pragma unroll
  for (int m = 0; m < M_; ++m)
#pragma unroll
    for (int n = 0; n < M_; ++n) {
      s[m][n] += __shfl_xor(s[m][n], 1);
      s[m][n] += __shfl_xor(s[m][n], 2);
      s[m][n] += __shfl_xor(s[m][n], 4);
    }

  float adj[M_][M_], rs[M_];
#pragma unroll
  for (int m = 0; m < M_; ++m) {
    float r = 0.f;
#pragma unroll
    for (int n = 0; n < M_; ++n) {
      float a = s[m][n] - s[n][m];
      float e = __builtin_exp2f(a * -4.328085123f);  // exp(-3a)
      float v = __builtin_amdgcn_rcpf(1.f + e);
      if (m == n) v += 1.f;
      adj[m][n] = v;
      r += v;
    }
    rs[m] = r;
  }

  for (int k = j; k < 25; k += 8) {
    int m = k / 5, n = k - m * 5;
    float v = adj[m][n] * __builtin_amdgcn_rcpf(rs[m]);
    size_t o = ((size_t)((b * M_ + m) * M_ + n)) * HW_ + px;
    if (isb) ((__hip_bfloat16*)out)[o] = __float2bfloat16(v);
    else     ((float*)out)[o] = v;
  }
}

// ---------------- launch ----------------
extern "C" void kernel_launch(void* const* d_in, const int* in_sizes, int n_in,
                              void* d_out, int out_size, void* d_ws, size_t ws_size,
                              hipStream_t stream) {
  const void* pts = d_in[0];
  const void* W1  = d_in[1];
  const void* b1  = d_in[2];
  const void* W2  = d_in[3];
  const void* b2  = d_in[4];

  char* ws = (char*)d_ws;
  _Float16* xin = (_Float16*)(ws + OFF_XIN);
  _Float16* wl1 = (_Float16*)(ws + OFF_WL1);
  _Float16* wl2 = (_Float16*)(ws + OFF_WL2);
  _Float16* n1  = (_Float16*)(ws + OFF_N1);
  _Float16* n2  = (_Float16*)(ws + OFF_N2);

  prep_kernel<<<dim3(4, H_, NIMG_ + 1), dim3(256), 0, stream>>>(pts, xin, W1, W2, wl1, wl2);
  conv_fused<<<dim3(256), dim3(512), 0, stream>>>(xin, wl1, wl2, b1, b2, pts, n1, n2);
  pairwise_kernel<<<dim3(B_ * HW_ * 8 / 256), dim3(256), 0, stream>>>(n1, n2, d_out, pts);
}